// Round 4
// baseline (1212.130 us; speedup 1.0000x reference)
//
#include <hip/hip_runtime.h>
#include <hip/hip_bf16.h>

#define HID 128
#define SDIM 48
#define NSTEP 511
#define TFULL 512
#define ROWS 16
#define XHS 200            // u16 stride: 400B, 16B-aligned
#define O1S 88             // u16 stride: 176B, 16B-aligned
#define WENC_OFF 98304
#define BIAS_BYTE_OFF 208896

typedef unsigned short u16;
typedef unsigned int   u32;
typedef __attribute__((ext_vector_type(8))) short short8;
typedef __attribute__((ext_vector_type(4))) float f32x4;

__device__ __forceinline__ float sigm(float x)  { return 1.0f/(1.0f+__expf(-x)); }
__device__ __forceinline__ float tanh_f(float x){ return 2.0f/(1.0f+__expf(-2.0f*x)) - 1.0f; }
__device__ __forceinline__ u16 f2bf(float f) {
  __hip_bfloat16 h = __float2bfloat16(f);
  return *reinterpret_cast<u16*>(&h);
}
__device__ __forceinline__ u32 pk2(float a, float b) {
  return (u32)f2bf(a) | ((u32)f2bf(b) << 16);
}
__device__ __forceinline__ short8 pack8(float4 a, float4 b) {
  short8 r;
  r[0]=(short)f2bf(a.x); r[1]=(short)f2bf(a.y); r[2]=(short)f2bf(a.z); r[3]=(short)f2bf(a.w);
  r[4]=(short)f2bf(b.x); r[5]=(short)f2bf(b.y); r[6]=(short)f2bf(b.z); r[7]=(short)f2bf(b.w);
  return r;
}

// xh layout (K dim): [0..47]=enc, [48..175]=h, [176..191]=0 (flow handled as rank-1)
__global__ void setup_weights(const float* __restrict__ w_ih, const float* __restrict__ w_hh,
                              const float* __restrict__ b_ih, const float* __restrict__ b_hh,
                              const float* __restrict__ enc_w1, const float* __restrict__ enc_w2,
                              u16* __restrict__ frags, float* __restrict__ bias) {
  int stride = gridDim.x * blockDim.x;
  int i0 = blockIdx.x * blockDim.x + threadIdx.x;
  for (int idx = i0; idx < 32*6*64*8; idx += stride) {
    int j  = idx & 7;
    int l  = (idx >> 3) & 63;
    int kt = (idx >> 9) % 6;
    int mt = (idx >> 9) / 6;
    int gr = mt*16 + (l & 15);
    int k  = kt*32 + (l >> 4)*8 + j;
    float v = 0.f;
    if (k < 48)       v = w_ih[gr*49 + 1 + k];          // enc part
    else if (k < 176) v = w_hh[gr*HID + (k - 48)];      // h part
    frags[idx] = f2bf(v);                               // k>=176 zero (flow via rank-1)
  }
  for (int idx = i0; idx < 2*3*2*64*8; idx += stride) {
    int j   = idx & 7;
    int l   = (idx >> 3) & 63;
    int kt  = (idx >> 9) & 1;
    int mt  = (idx >> 10) % 3;
    int lyr = (idx >> 10) / 3;
    int row = mt*16 + (l & 15);
    int k   = kt*32 + (l >> 4)*8 + j;
    float v = 0.f;
    if (k < SDIM) v = (lyr ? enc_w2 : enc_w1)[row*SDIM + k];
    frags[WENC_OFF + idx] = f2bf(v);
  }
  for (int idx = i0; idx < 512; idx += stride)
    bias[idx] = b_ih[idx] + b_hh[idx];
}

// 256 blocks x 512 threads (8 waves), persistent over 511 steps; ONE barrier/step.
// Wave w owns gate M-tiles {w, w+8, w+16, w+24}: units 16w..16w+15, i/f/g/o in-lane.
// Wave 7 additionally computes enc(st+1) fully intra-wave.
// pred(st-1) is recomputed by every lane from per-wave partials (s_pp ping-pong);
// flow enters the gates as a per-lane rank-1 update, not through the MFMA.
__global__ __launch_bounds__(512, 2)
void lstm_mfma(const float* __restrict__ y_flow,
               const float* __restrict__ x_statics,
               const int* __restrict__ twin_p,
               const float* __restrict__ enc_b1, const float* __restrict__ enc_b2,
               const float* __restrict__ out_w, const float* __restrict__ out_b,
               const float* __restrict__ w_ih,
               const u16* __restrict__ frags, const float* __restrict__ bias,
               float* __restrict__ out) {
  __shared__ __attribute__((aligned(16))) u16   s_xh[2][ROWS][XHS];
  __shared__ __attribute__((aligned(16))) u16   s_o1[ROWS][O1S];    // wave-7 private
  __shared__ __attribute__((aligned(16))) float s_pp[2][8][16];
  __shared__ __attribute__((aligned(16))) float s_bias[512];
  __shared__ __attribute__((aligned(16))) float s_eb1[SDIM];
  __shared__ __attribute__((aligned(16))) float s_eb2[SDIM];

  const int tid = threadIdx.x;
  const int blk = blockIdx.x;
  const int w  = tid >> 6;
  const int l  = tid & 63;
  const int lr = l & 15;     // batch row
  const int lg = l >> 4;     // lane group
  const size_t b0 = (size_t)blk * ROWS;

  // static gate fragments
  short8 wf[4][6];
  #pragma unroll
  for (int q = 0; q < 4; ++q)
    #pragma unroll
    for (int kt = 0; kt < 6; ++kt)
      wf[q][kt] = *(const short8*)(frags + (((w + 8*q)*6 + kt)*64 + l)*8);

  // flow (rank-1) weights: gate = (w+8q)*16 + lg*4 + r
  float wfl[4][4];
  #pragma unroll
  for (int q = 0; q < 4; ++q)
    #pragma unroll
    for (int r = 0; r < 4; ++r)
      wfl[q][r] = w_ih[((w + 8*q)*16 + lg*4 + r)*49];

  short8 we1[3][2], we2[3][2];
  if (w == 7) {
    #pragma unroll
    for (int mt = 0; mt < 3; ++mt)
      #pragma unroll
      for (int kt = 0; kt < 2; ++kt) {
        we1[mt][kt] = *(const short8*)(frags + WENC_OFF + (((0*3 + mt)*2 + kt)*64 + l)*8);
        we2[mt][kt] = *(const short8*)(frags + WENC_OFF + (((1*3 + mt)*2 + kt)*64 + l)*8);
      }
  }

  float owv[4];
  #pragma unroll
  for (int r = 0; r < 4; ++r) owv[r] = out_w[w*16 + lg*4 + r];
  const float ob  = out_b[0];
  const int   twc = twin_p[0] - 1;   // teacher iff t < twc

  // LDS init (zero + bias), barrier before targeted writes
  for (int i = tid; i < 2*ROWS*XHS; i += 512) ((u16*)s_xh)[i] = 0;
  for (int i = tid; i < ROWS*O1S;  i += 512) ((u16*)s_o1)[i] = 0;
  for (int i = tid; i < 2*8*16;    i += 512) ((float*)s_pp)[i] = 0.f;
  s_bias[tid] = bias[tid];
  if (tid < SDIM) { s_eb1[tid] = enc_b1[tid]; s_eb2[tid] = enc_b2[tid]; }
  __syncthreads();

  const float* xrow = x_statics + (size_t)(b0 + lr)*TFULL*SDIM;
  const float* yrow = y_flow    + (size_t)(b0 + lr)*TFULL;

  auto enc_step = [&](short8 bx0, short8 bx1, int pp) {
    f32x4 a[3];
    #pragma unroll
    for (int mt = 0; mt < 3; ++mt) a[mt] = *(const f32x4*)&s_eb1[mt*16 + lg*4];
    #pragma unroll
    for (int mt = 0; mt < 3; ++mt) {
      a[mt] = __builtin_amdgcn_mfma_f32_16x16x32_bf16(we1[mt][0], bx0, a[mt], 0, 0, 0);
      a[mt] = __builtin_amdgcn_mfma_f32_16x16x32_bf16(we1[mt][1], bx1, a[mt], 0, 0, 0);
    }
    #pragma unroll
    for (int mt = 0; mt < 3; ++mt) {
      *(u32*)&s_o1[lr][mt*16 + lg*4]     = pk2(fmaxf(a[mt][0],0.f), fmaxf(a[mt][1],0.f));
      *(u32*)&s_o1[lr][mt*16 + lg*4 + 2] = pk2(fmaxf(a[mt][2],0.f), fmaxf(a[mt][3],0.f));
    }
    asm volatile("s_waitcnt lgkmcnt(0)" ::: "memory");
    __builtin_amdgcn_sched_barrier(0);
    short8 bo0 = *(const short8*)&s_o1[lr][lg*8];
    short8 bo1 = *(const short8*)&s_o1[lr][32 + lg*8];
    f32x4 e[3];
    #pragma unroll
    for (int mt = 0; mt < 3; ++mt) e[mt] = *(const f32x4*)&s_eb2[mt*16 + lg*4];
    #pragma unroll
    for (int mt = 0; mt < 3; ++mt) {
      e[mt] = __builtin_amdgcn_mfma_f32_16x16x32_bf16(we2[mt][0], bo0, e[mt], 0, 0, 0);
      e[mt] = __builtin_amdgcn_mfma_f32_16x16x32_bf16(we2[mt][1], bo1, e[mt], 0, 0, 0);
    }
    #pragma unroll
    for (int mt = 0; mt < 3; ++mt) {
      *(u32*)&s_xh[pp][lr][mt*16 + lg*4]     = pk2(e[mt][0], e[mt][1]);
      *(u32*)&s_xh[pp][lr][mt*16 + lg*4 + 2] = pk2(e[mt][2], e[mt][3]);
    }
  };

  // prologue: enc(0) -> s_xh[0]; prefetch xs(1)
  float4 zf4 = make_float4(0.f, 0.f, 0.f, 0.f);
  float4 xn0a = zf4, xn0b = zf4, xn1a = zf4, xn1b = zf4;
  if (w == 7) {
    float4 c0a = *(const float4*)(xrow + lg*8);
    float4 c0b = *(const float4*)(xrow + lg*8 + 4);
    float4 c1a = zf4, c1b = zf4;
    if (lg < 2) {
      c1a = *(const float4*)(xrow + 32 + lg*8);
      c1b = *(const float4*)(xrow + 32 + lg*8 + 4);
    }
    enc_step(pack8(c0a, c0b), pack8(c1a, c1b), 0);
    xn0a = *(const float4*)(xrow + SDIM + lg*8);
    xn0b = *(const float4*)(xrow + SDIM + lg*8 + 4);
    if (lg < 2) {
      xn1a = *(const float4*)(xrow + SDIM + 32 + lg*8);
      xn1b = *(const float4*)(xrow + SDIM + 32 + lg*8 + 4);
    }
  }
  float c_reg[4] = {0.f, 0.f, 0.f, 0.f};
  __syncthreads();

  // main loop: ONE barrier per step
  for (int st = 0; st < NSTEP; ++st) {
    const int p  = st & 1;
    const int p2 = p ^ 1;

    // teacher flow (skipped entirely in free-running phase; L1-resident gather)
    float tf = 0.f;
    if (st < twc) tf = yrow[st];

    // B fragments (enc + h) from ping-pong buffer
    short8 bh[6];
    #pragma unroll
    for (int kt = 0; kt < 6; ++kt)
      bh[kt] = *(const short8*)&s_xh[p][lr][kt*32 + lg*8];

    // pred(st-1): every lane sums the 8 per-wave partials (broadcast reads)
    float pp_s = 0.f;
    #pragma unroll
    for (int ww = 0; ww < 8; ++ww) pp_s += s_pp[p][ww][lr];
    float pred_prev = pp_s + ob;
    if (st == 0) pred_prev = 0.f;
    if (st > 0 && l < 16 && (l >> 1) == w)
      out[(b0 + l)*NSTEP + (st - 1)] = pred_prev;
    const float flow = (st < twc) ? tf : pred_prev;

    // wave-7: pack xs(st+1), prefetch xs(st+2)
    short8 bx0 = {}, bx1 = {};
    if (w == 7) {
      bx0 = pack8(xn0a, xn0b);
      bx1 = pack8(xn1a, xn1b);
      const int tt = (st + 2 < TFULL) ? (st + 2) : (TFULL - 1);
      xn0a = *(const float4*)(xrow + (size_t)tt*SDIM + lg*8);
      xn0b = *(const float4*)(xrow + (size_t)tt*SDIM + lg*8 + 4);
      if (lg < 2) {
        xn1a = *(const float4*)(xrow + (size_t)tt*SDIM + 32 + lg*8);
        xn1b = *(const float4*)(xrow + (size_t)tt*SDIM + 32 + lg*8 + 4);
      }
    }

    // gates: bias + rank-1 flow + MFMA over enc/h
    f32x4 acc[4];
    #pragma unroll
    for (int q = 0; q < 4; ++q) {
      acc[q] = *(const f32x4*)&s_bias[(w + 8*q)*16 + lg*4];
      #pragma unroll
      for (int r = 0; r < 4; ++r) acc[q][r] += wfl[q][r]*flow;
    }
    #pragma unroll
    for (int kt = 0; kt < 6; ++kt)
      #pragma unroll
      for (int q = 0; q < 4; ++q)
        acc[q] = __builtin_amdgcn_mfma_f32_16x16x32_bf16(wf[q][kt], bh[kt], acc[q], 0, 0, 0);

    if (w == 7) {
      __builtin_amdgcn_s_setprio(1);
      enc_step(bx0, bx1, p2);            // enc(st+1) -> s_xh[p2]
      __builtin_amdgcn_s_setprio(0);
    }

    // LSTM cell
    float hv[4];
    float hsum = 0.f;
    #pragma unroll
    for (int r = 0; r < 4; ++r) {
      float iv = sigm(acc[0][r]);
      float fv = sigm(acc[1][r]);
      float gv = tanh_f(acc[2][r]);
      float ov = sigm(acc[3][r]);
      float c  = fv*c_reg[r] + iv*gv;
      c_reg[r] = c;
      hv[r] = ov*tanh_f(c);
      hsum += hv[r]*owv[r];
    }
    *(u32*)&s_xh[p2][lr][48 + w*16 + lg*4]     = pk2(hv[0], hv[1]);
    *(u32*)&s_xh[p2][lr][48 + w*16 + lg*4 + 2] = pk2(hv[2], hv[3]);
    hsum += __shfl_xor(hsum, 16);
    hsum += __shfl_xor(hsum, 32);
    if (l < 16) s_pp[p2][w][l] = hsum;
    __syncthreads();                     // the ONE barrier
  }

  // epilogue: pred(NSTEP-1)
  float pp_s = 0.f;
  #pragma unroll
  for (int ww = 0; ww < 8; ++ww) pp_s += s_pp[NSTEP & 1][ww][lr];
  if (l < 16 && (l >> 1) == w)
    out[(b0 + l)*NSTEP + (NSTEP - 1)] = pp_s + ob;
}

extern "C" void kernel_launch(void* const* d_in, const int* in_sizes, int n_in,
                              void* d_out, int out_size, void* d_ws, size_t ws_size,
                              hipStream_t stream) {
  const float* y_flow    = (const float*)d_in[0];
  const float* x_statics = (const float*)d_in[1];
  const int*   twin      = (const int*)  d_in[2];
  const float* enc_w1    = (const float*)d_in[3];
  const float* enc_b1    = (const float*)d_in[4];
  const float* enc_w2    = (const float*)d_in[5];
  const float* enc_b2    = (const float*)d_in[6];
  const float* w_ih      = (const float*)d_in[7];
  const float* w_hh      = (const float*)d_in[8];
  const float* b_ih      = (const float*)d_in[9];
  const float* b_hh      = (const float*)d_in[10];
  const float* out_w     = (const float*)d_in[11];
  const float* out_b     = (const float*)d_in[12];
  float* out = (float*)d_out;

  char* ws = (char*)d_ws;
  u16*   frags = (u16*)ws;
  float* bias  = (float*)(ws + BIAS_BYTE_OFF);

  setup_weights<<<128, 256, 0, stream>>>(w_ih, w_hh, b_ih, b_hh, enc_w1, enc_w2, frags, bias);
  lstm_mfma<<<256, 512, 0, stream>>>(y_flow, x_statics, twin,
                                     enc_b1, enc_b2, out_w, out_b, w_ih,
                                     frags, bias, out);
}

// Round 5
// 802.412 us; speedup vs baseline: 1.5106x; 1.5106x over previous
//
#include <hip/hip_runtime.h>
#include <hip/hip_bf16.h>

#define HID 128
#define SDIM 48
#define NSTEP 511
#define TFULL 512
#define ROWS 16
#define XHS 200            // u16 stride: 400B, 16B-aligned
#define O1S 88             // u16 stride: 176B, 16B-aligned
#define WENC_OFF 98304
#define BIAS_BYTE_OFF 208896

typedef unsigned short u16;
typedef unsigned int   u32;
typedef __attribute__((ext_vector_type(8))) short short8;
typedef __attribute__((ext_vector_type(4))) float f32x4;

__device__ __forceinline__ float frcp(float x)  { return __builtin_amdgcn_rcpf(x); }
__device__ __forceinline__ float sigm(float x)  { return frcp(1.0f + __expf(-x)); }
__device__ __forceinline__ float tanh_f(float x){ return 1.0f - 2.0f*frcp(1.0f + __expf(2.0f*x)); }
__device__ __forceinline__ u16 f2bf(float f) {
  __hip_bfloat16 h = __float2bfloat16(f);
  return *reinterpret_cast<u16*>(&h);
}
__device__ __forceinline__ u32 pk2(float a, float b) {
  return (u32)f2bf(a) | ((u32)f2bf(b) << 16);
}
__device__ __forceinline__ short8 pack8(float4 a, float4 b) {
  short8 r;
  r[0]=(short)f2bf(a.x); r[1]=(short)f2bf(a.y); r[2]=(short)f2bf(a.z); r[3]=(short)f2bf(a.w);
  r[4]=(short)f2bf(b.x); r[5]=(short)f2bf(b.y); r[6]=(short)f2bf(b.z); r[7]=(short)f2bf(b.w);
  return r;
}

// xh layout (K dim): [0..47]=enc, [48..175]=h, [176..191]=0 (flow handled as rank-1)
__global__ void setup_weights(const float* __restrict__ w_ih, const float* __restrict__ w_hh,
                              const float* __restrict__ b_ih, const float* __restrict__ b_hh,
                              const float* __restrict__ enc_w1, const float* __restrict__ enc_w2,
                              u16* __restrict__ frags, float* __restrict__ bias) {
  int stride = gridDim.x * blockDim.x;
  int i0 = blockIdx.x * blockDim.x + threadIdx.x;
  for (int idx = i0; idx < 32*6*64*8; idx += stride) {
    int j  = idx & 7;
    int l  = (idx >> 3) & 63;
    int kt = (idx >> 9) % 6;
    int mt = (idx >> 9) / 6;
    int gr = mt*16 + (l & 15);
    int k  = kt*32 + (l >> 4)*8 + j;
    float v = 0.f;
    if (k < 48)       v = w_ih[gr*49 + 1 + k];          // enc part
    else if (k < 176) v = w_hh[gr*HID + (k - 48)];      // h part
    frags[idx] = f2bf(v);                               // k>=176 zero (flow via rank-1)
  }
  for (int idx = i0; idx < 2*3*2*64*8; idx += stride) {
    int j   = idx & 7;
    int l   = (idx >> 3) & 63;
    int kt  = (idx >> 9) & 1;
    int mt  = (idx >> 10) % 3;
    int lyr = (idx >> 10) / 3;
    int row = mt*16 + (l & 15);
    int k   = kt*32 + (l >> 4)*8 + j;
    float v = 0.f;
    if (k < SDIM) v = (lyr ? enc_w2 : enc_w1)[row*SDIM + k];
    frags[WENC_OFF + idx] = f2bf(v);
  }
  for (int idx = i0; idx < 512; idx += stride)
    bias[idx] = b_ih[idx] + b_hh[idx];
}

// 256 blocks x 512 threads (8 waves), persistent over 511 steps; ONE barrier/step.
// Wave w owns gate M-tiles {w, w+8, w+16, w+24}: units 16w..16w+15, i/f/g/o in-lane.
// Wave 7 additionally computes enc(st+1) fully intra-wave.
// pred(st-1) recomputed by every lane from per-wave partials (s_pp ping-pong);
// flow enters the gates as a per-lane rank-1 update ADDED AFTER the MFMA chain.
__global__ __launch_bounds__(512, 2)
void lstm_mfma(const float* __restrict__ y_flow,
               const float* __restrict__ x_statics,
               const int* __restrict__ twin_p,
               const float* __restrict__ enc_b1, const float* __restrict__ enc_b2,
               const float* __restrict__ out_w, const float* __restrict__ out_b,
               const float* __restrict__ w_ih,
               const u16* __restrict__ frags, const float* __restrict__ bias,
               float* __restrict__ out) {
  __shared__ __attribute__((aligned(16))) u16   s_xh[2][ROWS][XHS];
  __shared__ __attribute__((aligned(16))) u16   s_o1[ROWS][O1S];    // wave-7 private
  __shared__ __attribute__((aligned(16))) float s_pp[2][ROWS][8];   // [row][wave]
  __shared__ __attribute__((aligned(16))) float s_bias[512];
  __shared__ __attribute__((aligned(16))) float s_eb1[SDIM];
  __shared__ __attribute__((aligned(16))) float s_eb2[SDIM];

  const int tid = threadIdx.x;
  const int blk = blockIdx.x;
  const int w  = tid >> 6;
  const int l  = tid & 63;
  const int lr = l & 15;     // batch row
  const int lg = l >> 4;     // lane group
  const size_t b0 = (size_t)blk * ROWS;

  // static gate fragments (live in unified VGPR/AGPR file, feed MFMA A directly)
  short8 wf[4][6];
  #pragma unroll
  for (int q = 0; q < 4; ++q)
    #pragma unroll
    for (int kt = 0; kt < 6; ++kt)
      wf[q][kt] = *(const short8*)(frags + (((w + 8*q)*6 + kt)*64 + l)*8);

  // flow (rank-1) weights: gate = (w+8q)*16 + lg*4 + r
  float wfl[4][4];
  #pragma unroll
  for (int q = 0; q < 4; ++q)
    #pragma unroll
    for (int r = 0; r < 4; ++r)
      wfl[q][r] = w_ih[((w + 8*q)*16 + lg*4 + r)*49];

  short8 we1[3][2], we2[3][2];
  if (w == 7) {
    #pragma unroll
    for (int mt = 0; mt < 3; ++mt)
      #pragma unroll
      for (int kt = 0; kt < 2; ++kt) {
        we1[mt][kt] = *(const short8*)(frags + WENC_OFF + (((0*3 + mt)*2 + kt)*64 + l)*8);
        we2[mt][kt] = *(const short8*)(frags + WENC_OFF + (((1*3 + mt)*2 + kt)*64 + l)*8);
      }
  }

  float owv[4];
  #pragma unroll
  for (int r = 0; r < 4; ++r) owv[r] = out_w[w*16 + lg*4 + r];
  const float ob  = out_b[0];
  const int   twc = twin_p[0] - 1;   // teacher iff t < twc

  // LDS init (zero + bias), barrier before targeted writes
  for (int i = tid; i < 2*ROWS*XHS; i += 512) ((u16*)s_xh)[i] = 0;
  for (int i = tid; i < ROWS*O1S;  i += 512) ((u16*)s_o1)[i] = 0;
  for (int i = tid; i < 2*ROWS*8;  i += 512) ((float*)s_pp)[i] = 0.f;
  s_bias[tid] = bias[tid];
  if (tid < SDIM) { s_eb1[tid] = enc_b1[tid]; s_eb2[tid] = enc_b2[tid]; }
  __syncthreads();

  const float* xrow = x_statics + (size_t)(b0 + lr)*TFULL*SDIM;
  const float* yrow = y_flow    + (size_t)(b0 + lr)*TFULL;

  auto enc_step = [&](short8 bx0, short8 bx1, int pp) {
    f32x4 a[3];
    #pragma unroll
    for (int mt = 0; mt < 3; ++mt) a[mt] = *(const f32x4*)&s_eb1[mt*16 + lg*4];
    #pragma unroll
    for (int mt = 0; mt < 3; ++mt) {
      a[mt] = __builtin_amdgcn_mfma_f32_16x16x32_bf16(we1[mt][0], bx0, a[mt], 0, 0, 0);
      a[mt] = __builtin_amdgcn_mfma_f32_16x16x32_bf16(we1[mt][1], bx1, a[mt], 0, 0, 0);
    }
    #pragma unroll
    for (int mt = 0; mt < 3; ++mt) {
      *(u32*)&s_o1[lr][mt*16 + lg*4]     = pk2(fmaxf(a[mt][0],0.f), fmaxf(a[mt][1],0.f));
      *(u32*)&s_o1[lr][mt*16 + lg*4 + 2] = pk2(fmaxf(a[mt][2],0.f), fmaxf(a[mt][3],0.f));
    }
    asm volatile("s_waitcnt lgkmcnt(0)" ::: "memory");
    __builtin_amdgcn_sched_barrier(0);
    short8 bo0 = *(const short8*)&s_o1[lr][lg*8];
    short8 bo1 = *(const short8*)&s_o1[lr][32 + lg*8];
    f32x4 e[3];
    #pragma unroll
    for (int mt = 0; mt < 3; ++mt) e[mt] = *(const f32x4*)&s_eb2[mt*16 + lg*4];
    #pragma unroll
    for (int mt = 0; mt < 3; ++mt) {
      e[mt] = __builtin_amdgcn_mfma_f32_16x16x32_bf16(we2[mt][0], bo0, e[mt], 0, 0, 0);
      e[mt] = __builtin_amdgcn_mfma_f32_16x16x32_bf16(we2[mt][1], bo1, e[mt], 0, 0, 0);
    }
    #pragma unroll
    for (int mt = 0; mt < 3; ++mt) {
      *(u32*)&s_xh[pp][lr][mt*16 + lg*4]     = pk2(e[mt][0], e[mt][1]);
      *(u32*)&s_xh[pp][lr][mt*16 + lg*4 + 2] = pk2(e[mt][2], e[mt][3]);
    }
  };

  // prologue: enc(0) -> s_xh[0]; prefetch xs(1)
  float4 zf4 = make_float4(0.f, 0.f, 0.f, 0.f);
  float4 xn0a = zf4, xn0b = zf4, xn1a = zf4, xn1b = zf4;
  if (w == 7) {
    float4 c0a = *(const float4*)(xrow + lg*8);
    float4 c0b = *(const float4*)(xrow + lg*8 + 4);
    float4 c1a = zf4, c1b = zf4;
    if (lg < 2) {
      c1a = *(const float4*)(xrow + 32 + lg*8);
      c1b = *(const float4*)(xrow + 32 + lg*8 + 4);
    }
    enc_step(pack8(c0a, c0b), pack8(c1a, c1b), 0);
    xn0a = *(const float4*)(xrow + SDIM + lg*8);
    xn0b = *(const float4*)(xrow + SDIM + lg*8 + 4);
    if (lg < 2) {
      xn1a = *(const float4*)(xrow + SDIM + 32 + lg*8);
      xn1b = *(const float4*)(xrow + SDIM + 32 + lg*8 + 4);
    }
  }
  float c_reg[4] = {0.f, 0.f, 0.f, 0.f};
  __syncthreads();

  // main loop: ONE barrier per step
  for (int st = 0; st < NSTEP; ++st) {
    const int p  = st & 1;
    const int p2 = p ^ 1;

    // B fragments (enc + h) from ping-pong buffer — front of MFMA chain
    short8 bh[6];
    #pragma unroll
    for (int kt = 0; kt < 6; ++kt)
      bh[kt] = *(const short8*)&s_xh[p][lr][kt*32 + lg*8];

    // gates: bias + MFMA over enc/h (flow rank-1 added AFTER, in the cell)
    f32x4 acc[4];
    #pragma unroll
    for (int q = 0; q < 4; ++q) acc[q] = *(const f32x4*)&s_bias[(w + 8*q)*16 + lg*4];
    #pragma unroll
    for (int kt = 0; kt < 6; ++kt)
      #pragma unroll
      for (int q = 0; q < 4; ++q)
        acc[q] = __builtin_amdgcn_mfma_f32_16x16x32_bf16(wf[q][kt], bh[kt], acc[q], 0, 0, 0);

    // pred(st-1): 2 x b128 from s_pp[p][lr][0..7] — overlaps with MFMA chain
    f32x4 pa = *(const f32x4*)&s_pp[p][lr][0];
    f32x4 pb = *(const f32x4*)&s_pp[p][lr][4];
    float pp_s = ((pa[0]+pa[1]) + (pa[2]+pa[3])) + ((pb[0]+pb[1]) + (pb[2]+pb[3]));
    float pred_prev = pp_s + ob;
    if (st == 0) pred_prev = 0.f;
    if (st > 0 && l < 16 && (l >> 1) == w)
      out[(b0 + l)*NSTEP + (st - 1)] = pred_prev;

    float tf = 0.f;
    if (st < twc) tf = yrow[st];
    const float flow = (st < twc) ? tf : pred_prev;

    // wave-7: pack xs(st+1), prefetch xs(st+2), run encoder
    if (w == 7) {
      short8 bx0 = pack8(xn0a, xn0b);
      short8 bx1 = pack8(xn1a, xn1b);
      const int tt = (st + 2 < TFULL) ? (st + 2) : (TFULL - 1);
      xn0a = *(const float4*)(xrow + (size_t)tt*SDIM + lg*8);
      xn0b = *(const float4*)(xrow + (size_t)tt*SDIM + lg*8 + 4);
      if (lg < 2) {
        xn1a = *(const float4*)(xrow + (size_t)tt*SDIM + 32 + lg*8);
        xn1b = *(const float4*)(xrow + (size_t)tt*SDIM + 32 + lg*8 + 4);
      }
      __builtin_amdgcn_s_setprio(1);
      enc_step(bx0, bx1, p2);            // enc(st+1) -> s_xh[p2]
      __builtin_amdgcn_s_setprio(0);
    }

    // LSTM cell: gate = acc + wfl*flow; fast sigm/tanh (v_rcp)
    float hv[4];
    float hsum = 0.f;
    #pragma unroll
    for (int r = 0; r < 4; ++r) {
      float g_i = acc[0][r] + wfl[0][r]*flow;
      float g_f = acc[1][r] + wfl[1][r]*flow;
      float g_g = acc[2][r] + wfl[2][r]*flow;
      float g_o = acc[3][r] + wfl[3][r]*flow;
      float iv = sigm(g_i);
      float fv = sigm(g_f);
      float gv = tanh_f(g_g);
      float ov = sigm(g_o);
      float c  = fv*c_reg[r] + iv*gv;
      c_reg[r] = c;
      hv[r] = ov*tanh_f(c);
      hsum += hv[r]*owv[r];
    }
    *(u32*)&s_xh[p2][lr][48 + w*16 + lg*4]     = pk2(hv[0], hv[1]);
    *(u32*)&s_xh[p2][lr][48 + w*16 + lg*4 + 2] = pk2(hv[2], hv[3]);
    hsum += __shfl_xor(hsum, 16);
    hsum += __shfl_xor(hsum, 32);
    if (l < 16) s_pp[p2][l][w] = hsum;
    __syncthreads();                     // the ONE barrier
  }

  // epilogue: pred(NSTEP-1)
  f32x4 pa = *(const f32x4*)&s_pp[NSTEP & 1][lr][0];
  f32x4 pb = *(const f32x4*)&s_pp[NSTEP & 1][lr][4];
  float pp_s = ((pa[0]+pa[1]) + (pa[2]+pa[3])) + ((pb[0]+pb[1]) + (pb[2]+pb[3]));
  if (l < 16 && (l >> 1) == w)
    out[(b0 + l)*NSTEP + (NSTEP - 1)] = pp_s + ob;
}

extern "C" void kernel_launch(void* const* d_in, const int* in_sizes, int n_in,
                              void* d_out, int out_size, void* d_ws, size_t ws_size,
                              hipStream_t stream) {
  const float* y_flow    = (const float*)d_in[0];
  const float* x_statics = (const float*)d_in[1];
  const int*   twin      = (const int*)  d_in[2];
  const float* enc_w1    = (const float*)d_in[3];
  const float* enc_b1    = (const float*)d_in[4];
  const float* enc_w2    = (const float*)d_in[5];
  const float* enc_b2    = (const float*)d_in[6];
  const float* w_ih      = (const float*)d_in[7];
  const float* w_hh      = (const float*)d_in[8];
  const float* b_ih      = (const float*)d_in[9];
  const float* b_hh      = (const float*)d_in[10];
  const float* out_w     = (const float*)d_in[11];
  const float* out_b     = (const float*)d_in[12];
  float* out = (float*)d_out;

  char* ws = (char*)d_ws;
  u16*   frags = (u16*)ws;
  float* bias  = (float*)(ws + BIAS_BYTE_OFF);

  setup_weights<<<128, 256, 0, stream>>>(w_ih, w_hh, b_ih, b_hh, enc_w1, enc_w2, frags, bias);
  lstm_mfma<<<256, 512, 0, stream>>>(y_flow, x_statics, twin,
                                     enc_b1, enc_b2, out_w, out_b, w_ih,
                                     frags, bias, out);
}